// Round 3
// baseline (381.986 us; speedup 1.0000x reference)
//
#include <hip/hip_runtime.h>

// Problem constants
#define B 8
#define N 4096
#define C 128
#define C2 256          // K-dim of fused GEMM: [ptl | s]
#define KNN 21          // top-(K+1), drop nearest
#define CAP 17          // per-lane append buffer capacity

typedef unsigned long long u64;
typedef unsigned int u32;
typedef unsigned short u16;

__device__ __forceinline__ float bf2f(u16 u) {
    return __uint_as_float(((u32)u) << 16);
}
__device__ __forceinline__ u16 f2bf(float f) {  // round-to-nearest-even
    u32 x = __float_as_uint(f);
    return (u16)((x + 0x7FFFu + ((x >> 16) & 1u)) >> 16);
}

// ---------------------------------------------------------------------------
// K1a: transpose + leaky_relu: points (B,C,N) f32 -> X[b][n][c] (c<128) bf16
// ---------------------------------------------------------------------------
__global__ __launch_bounds__(256) void k_transpose_lrelu(
        const float* __restrict__ pts, u16* __restrict__ X) {
    __shared__ u16 tile[32][33];
    int b  = blockIdx.z;
    int c0 = blockIdx.y * 32;
    int n0 = blockIdx.x * 32;
    int tx = threadIdx.x, ty = threadIdx.y;   // 32 x 8
    const float* src = pts + (size_t)b * C * N;
    #pragma unroll
    for (int i = 0; i < 32; i += 8) {
        float v = src[(size_t)(c0 + ty + i) * N + n0 + tx];
        if (v < 0.f) v = __fmul_rn(v, 0.01f);
        tile[ty + i][tx] = f2bf(v);
    }
    __syncthreads();
    u16* dst = X + (size_t)b * N * C2;
    #pragma unroll
    for (int i = 0; i < 32; i += 8) {
        dst[(size_t)(n0 + ty + i) * C2 + (c0 + tx)] = tile[tx][ty + i];
    }
}

// ---------------------------------------------------------------------------
// K1b: build Wt[c][o] (c in [0,256)): c<128 -> Wc[o][c], else Wg[o][c-128]
// Stored as bf16? NO — weights feed the fp32 FMA GEMM; store fp32 to avoid
// extra quantization (error budget goes to X only).
// ---------------------------------------------------------------------------
__global__ __launch_bounds__(256) void k_build_wt(
        const float* __restrict__ Wc, const float* __restrict__ Wg,
        float* __restrict__ Wt) {
    int e = blockIdx.x * 256 + threadIdx.x;   // 32768 total
    int c = e >> 7, o = e & 127;
    Wt[e] = (c < 128) ? Wc[o * 128 + c] : Wg[o * 128 + (c - 128)];
}

// ---------------------------------------------------------------------------
// K2: exact KNN (top-21 by (sq, idx), drop min) + neighbor-feature gather-sum.
// Block: 256 thr = 4 waves. 64 queries/block (query = lane). Wave w handles
// candidate quarter [w*1024, w*1024+1024). Per-lane sorted-21 in registers,
// LDS append buffer, wave-uniform compaction. 4-way merge by wave 0, then
// cooperative gather of 20 neighbor rows -> s written to X[b][n][128..255].
// ---------------------------------------------------------------------------
__global__ __launch_bounds__(256) void k_knn_gather(
        const float* __restrict__ xyz, u16* __restrict__ X) {
    __shared__ __align__(16) char lds[51200];
    float4* stg = (float4*)lds;                       // [4][256] (phase A)
    u64*    buf = (u64*)(lds + 16384);                // [256][CAP] (phase A)
    u64*    mg  = (u64*)lds;                          // [256][21] (phase B)
    __shared__ u16 win[64 * KNN];

    int tid = threadIdx.x;
    int w = tid >> 6, l = tid & 63;
    int b = blockIdx.y;
    int n0 = blockIdx.x * 64;
    int nq = n0 + l;

    const float* xz = xyz + (size_t)b * 3 * N;
    // query point (np formula: ((x*x + y*y) + z*z))
    float qx = xz[nq], qy = xz[N + nq], qz = xz[2 * N + nq];
    float snq = __fadd_rn(__fadd_rn(__fmul_rn(qx, qx), __fmul_rn(qy, qy)),
                          __fmul_rn(qz, qz));

    u64 slot[KNN];
    #pragma unroll
    for (int i = 0; i < KNN; ++i) slot[i] = ~0ull;
    int cnt = 0;
    float4* mystg = stg + w * 256;
    u64* mybuf = buf + tid * CAP;

    auto compact = [&]() {
        for (int i = 0; i < CAP; ++i) {
            bool act = (i < cnt);
            if (__ballot(act) == 0ull) break;
            u64 item = mybuf[i];                      // own region, in-bounds
            bool ins = act && (item < slot[20]);
            if (__ballot(ins) != 0ull) {
                if (ins) slot[20] = item;
                #pragma unroll
                for (int t = 19; t >= 0; --t) {       // bubble toward front
                    u64 a = slot[t], bb = slot[t + 1];
                    u64 lo = a < bb ? a : bb;
                    u64 hi = a < bb ? bb : a;
                    slot[t] = lo; slot[t + 1] = hi;
                }
            }
        }
        cnt = 0;
    };

    for (int sc = 0; sc < 4; ++sc) {
        int m0 = w * 1024 + sc * 256;
        // stage 256 candidates (x,y,z,sq_norm) into this wave's region
        #pragma unroll
        for (int r = 0; r < 4; ++r) {
            int j = l + 64 * r, m = m0 + j;
            float x = xz[m], y = xz[N + m], z = xz[2 * N + m];
            float sn = __fadd_rn(__fadd_rn(__fmul_rn(x, x), __fmul_rn(y, y)),
                                 __fmul_rn(z, z));
            mystg[j] = make_float4(x, y, z, sn);
        }
        asm volatile("s_waitcnt lgkmcnt(0)" ::: "memory");
        for (int j = 0; j < 256; ++j) {
            float4 cp = mystg[j];                     // broadcast read
            int m = m0 + j;
            float dot = __fadd_rn(__fadd_rn(__fmul_rn(qx, cp.x),
                                            __fmul_rn(qy, cp.y)),
                                  __fmul_rn(qz, cp.z));
            float sq = __fadd_rn(__fsub_rn(snq, __fadd_rn(dot, dot)), cp.w);
            u32 kb = __float_as_uint(sq);
            kb = (kb & 0x80000000u) ? ~kb : (kb | 0x80000000u);  // sortable
            u64 key = ((u64)kb << 12) | (u64)m;       // tie-break by index
            if (key < slot[20]) { mybuf[cnt] = key; cnt++; }
            if (__ballot(cnt >= CAP) != 0ull) compact();
        }
    }
    compact();

    __syncthreads();                                  // phase-A buffers dead
    #pragma unroll
    for (int j = 0; j < KNN; ++j) mg[(w * 64 + l) * KNN + j] = slot[j];
    __syncthreads();

    if (w == 0) {                                     // 4-way merge per query
        int p0 = 0, p1 = 0, p2 = 0, p3 = 0;
        for (int j = 0; j < KNN; ++j) {
            u64 c0 = mg[(0 * 64 + l) * KNN + p0];
            u64 c1 = mg[(1 * 64 + l) * KNN + p1];
            u64 c2 = mg[(2 * 64 + l) * KNN + p2];
            u64 c3 = mg[(3 * 64 + l) * KNN + p3];
            u64 m01 = c0 < c1 ? c0 : c1; int s01 = c0 < c1 ? 0 : 1;
            u64 m23 = c2 < c3 ? c2 : c3; int s23 = c2 < c3 ? 2 : 3;
            u64 mm = m01 < m23 ? m01 : m23;
            int sel = m01 < m23 ? s01 : s23;
            win[l * KNN + j] = (u16)(mm & 0xFFFu);
            p0 += (sel == 0); p1 += (sel == 1); p2 += (sel == 2); p3 += (sel == 3);
        }
    }
    __syncthreads();

    // gather-sum: wave w handles 16 queries; lane covers channels 2l, 2l+1
    const u16* Xb = X + (size_t)b * N * C2;
    for (int qq = 0; qq < 16; ++qq) {
        int q = w * 16 + qq;
        float f0 = 0.f, f1 = 0.f;
        for (int j = 1; j < KNN; ++j) {               // skip nearest (j=0)
            int m = win[q * KNN + j];
            u32 u2 = *(const u32*)(Xb + (size_t)m * C2 + 2 * l);
            f0 += bf2f((u16)(u2 & 0xFFFFu));
            f1 += bf2f((u16)(u2 >> 16));
        }
        u16* dst = X + ((size_t)b * N + n0 + q) * C2 + 128 + 2 * l;
        *(u32*)dst = ((u32)f2bf(f1) << 16) | (u32)f2bf(f0);
    }
}

// ---------------------------------------------------------------------------
// K3: out[b][o][n] = (Wt[:,o] . X[b][n][:] + bc[o] + 20*bg[o]) / 21
//                    + points[b][o][n]      (fp32 out)
// ---------------------------------------------------------------------------
__global__ __launch_bounds__(128) void k_gemm(
        const u16* __restrict__ X, const float* __restrict__ Wt,
        const float* __restrict__ pts, const float* __restrict__ bc,
        const float* __restrict__ bg, float* __restrict__ out) {
    __shared__ float Xl[256 * 36];                    // [c][n], pad to 36
    int b = blockIdx.y;
    int n0 = blockIdx.x * 32;
    int t = threadIdx.x;                              // 0..127

    const u16* Xb = X + (size_t)b * N * C2;
    for (int e = t; e < 8192; e += 128) {
        int c = e & 255, n = e >> 8;
        Xl[c * 36 + n] = bf2f(Xb[(size_t)(n0 + n) * C2 + c]);
    }
    __syncthreads();

    float acc[32];
    #pragma unroll
    for (int j = 0; j < 32; ++j) acc[j] = 0.f;
    int o = t;
    for (int c = 0; c < 256; ++c) {
        float wv = Wt[c * 128 + o];
        #pragma unroll
        for (int j = 0; j < 32; j += 4) {
            float4 xv = *(float4*)&Xl[c * 36 + j];
            acc[j]     = __fmaf_rn(wv, xv.x, acc[j]);
            acc[j + 1] = __fmaf_rn(wv, xv.y, acc[j + 1]);
            acc[j + 2] = __fmaf_rn(wv, xv.z, acc[j + 2]);
            acc[j + 3] = __fmaf_rn(wv, xv.w, acc[j + 3]);
        }
    }
    float bias = bc[o] + 20.f * bg[o];
    const float inv21 = 1.0f / 21.0f;

    __syncthreads();                                  // reuse Xl as [o][n]
    float* ol = Xl;
    #pragma unroll
    for (int j = 0; j < 32; ++j) ol[o * 36 + j] = (acc[j] + bias) * inv21;
    __syncthreads();

    const float* pb = pts + (size_t)b * C * N;
    float* ob = out + (size_t)b * C * N;
    for (int e = t; e < 4096; e += 128) {
        int o2 = e >> 5, n = e & 31;
        ob[(size_t)o2 * N + n0 + n] = ol[o2 * 36 + n] + pb[(size_t)o2 * N + n0 + n];
    }
}

// ---------------------------------------------------------------------------
extern "C" void kernel_launch(void* const* d_in, const int* in_sizes, int n_in,
                              void* d_out, int out_size, void* d_ws, size_t ws_size,
                              hipStream_t stream) {
    const float* xyz = (const float*)d_in[0];
    const float* pts = (const float*)d_in[1];
    const float* Wc  = (const float*)d_in[2];
    const float* bc  = (const float*)d_in[3];
    const float* Wg  = (const float*)d_in[4];
    const float* bg  = (const float*)d_in[5];
    float* out = (float*)d_out;

    char* ws = (char*)d_ws;
    u16*   X  = (u16*)ws;                               // B*N*C2 bf16 = 16 MB
    float* Wt = (float*)(ws + (size_t)B * N * C2 * 2);  // 256*128 f32 = 128 KB

    k_transpose_lrelu<<<dim3(N / 32, C / 32, B), dim3(32, 8), 0, stream>>>(pts, X);
    k_build_wt<<<dim3(128), dim3(256), 0, stream>>>(Wc, Wg, Wt);
    k_knn_gather<<<dim3(N / 64, B), dim3(256), 0, stream>>>(xyz, X);
    k_gemm<<<dim3(N / 32, B), dim3(128), 0, stream>>>(X, Wt, pts, bc, bg, out);
}

// Round 4
// 306.014 us; speedup vs baseline: 1.2483x; 1.2483x over previous
//
#include <hip/hip_runtime.h>

// Problem constants
#define B 8
#define N 4096
#define C 128
#define C2 256          // K-dim of fused GEMM: [ptl | s]
#define KNN 21          // top-(K+1), drop nearest
#define CAP 22          // per-lane append buffer capacity (slots 0..21)

typedef unsigned long long u64;
typedef unsigned int u32;
typedef unsigned short u16;

typedef __attribute__((ext_vector_type(8))) short bf16x8;
typedef __attribute__((ext_vector_type(4))) float f32x4;

__device__ __forceinline__ float bf2f(u16 u) {
    return __uint_as_float(((u32)u) << 16);
}
__device__ __forceinline__ u16 f2bf(float f) {  // round-to-nearest-even
    u32 x = __float_as_uint(f);
    return (u16)((x + 0x7FFFu + ((x >> 16) & 1u)) >> 16);
}

// ---------------------------------------------------------------------------
// K1a: transpose + leaky_relu: points (B,C,N) f32 -> X[b][n][c] (c<128) bf16
// ---------------------------------------------------------------------------
__global__ __launch_bounds__(256) void k_transpose_lrelu(
        const float* __restrict__ pts, u16* __restrict__ X) {
    __shared__ u16 tile[32][33];
    int b  = blockIdx.z;
    int c0 = blockIdx.y * 32;
    int n0 = blockIdx.x * 32;
    int tx = threadIdx.x, ty = threadIdx.y;   // 32 x 8
    const float* src = pts + (size_t)b * C * N;
    #pragma unroll
    for (int i = 0; i < 32; i += 8) {
        float v = src[(size_t)(c0 + ty + i) * N + n0 + tx];
        if (v < 0.f) v = __fmul_rn(v, 0.01f);
        tile[ty + i][tx] = f2bf(v);
    }
    __syncthreads();
    u16* dst = X + (size_t)b * N * C2;
    #pragma unroll
    for (int i = 0; i < 32; i += 8) {
        dst[(size_t)(n0 + ty + i) * C2 + (c0 + tx)] = tile[tx][ty + i];
    }
}

// ---------------------------------------------------------------------------
// K1b: pack Wt bf16 [o][c], c<128 -> Wc[o][c], else Wg[o][c-128]
// (row-major [o][256] so MFMA A-fragments are contiguous 16B chunks)
// ---------------------------------------------------------------------------
__global__ __launch_bounds__(256) void k_pack_w(
        const float* __restrict__ Wc, const float* __restrict__ Wg,
        u16* __restrict__ Wt) {
    int e = blockIdx.x * 256 + threadIdx.x;   // 32768 total
    int o = e >> 8, c = e & 255;
    float v = (c < 128) ? Wc[o * 128 + c] : Wg[o * 128 + (c - 128)];
    Wt[e] = f2bf(v);
}

// ---------------------------------------------------------------------------
// K2: exact KNN (top-21 by (sq, idx), drop min) + neighbor-feature gather-sum.
// 256 thr = 4 waves; 64 queries/block (query = lane); wave w scans candidates
// [w*1024, +1024). Hot loop: chunk-8 unrolled, unconditional b64 append at
// buf[cnt][tid] (bank-friendly), u32 threshold compare, one ballot / 8 cands.
// Compact: divergence-free neutral-element bubble into sorted-21 registers.
// ---------------------------------------------------------------------------
__global__ __launch_bounds__(256) void k_knn_gather(
        const float* __restrict__ xyz, u16* __restrict__ X) {
    __shared__ __align__(16) char lds[61440];
    float4* stg = (float4*)lds;                       // [4][256]   (phase A)
    u64*    buf = (u64*)(lds + 16384);                // [CAP][256] (phase A)
    u64*    mg  = (u64*)lds;                          // [256][21]  (phase B)
    __shared__ u16 win[64 * KNN];

    int tid = threadIdx.x;
    int w = tid >> 6, l = tid & 63;
    int b = blockIdx.y;
    int n0 = blockIdx.x * 64;
    int nq = n0 + l;

    const float* xz = xyz + (size_t)b * 3 * N;
    // query point (np formula: ((x*x + y*y) + z*z))
    float qx = xz[nq], qy = xz[N + nq], qz = xz[2 * N + nq];
    float snq = __fadd_rn(__fadd_rn(__fmul_rn(qx, qx), __fmul_rn(qy, qy)),
                          __fmul_rn(qz, qz));

    u64 slot[KNN];
    #pragma unroll
    for (int i = 0; i < KNN; ++i) slot[i] = ~0ull;
    int cnt = 0;
    u32 thr_kb = 0xFFFFFFFFu;
    float4* mystg = stg + w * 256;

    auto compact = [&]() {
        #pragma unroll 1
        for (int i = 0; i < CAP; ++i) {
            if (__ballot(i < cnt) == 0ull) break;
            u64 item = buf[i * 256 + tid];
            bool ins = (i < cnt) && (item < slot[20]);
            if (__ballot(ins) != 0ull) {
                u64 cnd = ins ? item : ~0ull;         // neutral: no-op bubble
                slot[20] = cnd < slot[20] ? cnd : slot[20];
                #pragma unroll
                for (int t = 19; t >= 0; --t) {
                    u64 a = slot[t], bb = slot[t + 1];
                    u64 lo = a < bb ? a : bb;
                    u64 hi = a < bb ? bb : a;
                    slot[t] = lo; slot[t + 1] = hi;
                }
            }
        }
        cnt = 0;
        thr_kb = (u32)(slot[20] >> 32);
    };

    for (int sc = 0; sc < 4; ++sc) {
        int m0 = w * 1024 + sc * 256;
        // stage 256 candidates (x,y,z,sq_norm) into this wave's region
        #pragma unroll
        for (int r = 0; r < 4; ++r) {
            int j = l + 64 * r, m = m0 + j;
            float x = xz[m], y = xz[N + m], z = xz[2 * N + m];
            float sn = __fadd_rn(__fadd_rn(__fmul_rn(x, x), __fmul_rn(y, y)),
                                 __fmul_rn(z, z));
            mystg[j] = make_float4(x, y, z, sn);
        }
        asm volatile("s_waitcnt lgkmcnt(0)" ::: "memory");
        for (int cc = 0; cc < 256; cc += 8) {
            #pragma unroll
            for (int j = 0; j < 8; ++j) {
                float4 cp = mystg[cc + j];            // wave-broadcast read
                int m = m0 + cc + j;
                float dot = __fadd_rn(__fadd_rn(__fmul_rn(qx, cp.x),
                                                __fmul_rn(qy, cp.y)),
                                      __fmul_rn(qz, cp.z));
                float sq = __fadd_rn(__fsub_rn(snq, __fadd_rn(dot, dot)), cp.w);
                u32 bits = __float_as_uint(sq);
                u32 kb = bits ^ (0x80000000u | (u32)(((int)bits) >> 31));
                buf[cnt * 256 + tid] = ((u64)kb << 32) | (u32)m;  // uncond.
                cnt += (kb <= thr_kb);
            }
            if (__ballot(cnt >= 15) != 0ull) compact();
        }
    }
    compact();

    __syncthreads();                                  // phase-A buffers dead
    #pragma unroll
    for (int j = 0; j < KNN; ++j) mg[(w * 64 + l) * KNN + j] = slot[j];
    __syncthreads();

    if (w == 0) {                                     // 4-way merge per query
        int p0 = 0, p1 = 0, p2 = 0, p3 = 0;
        for (int j = 0; j < KNN; ++j) {
            u64 c0 = mg[(0 * 64 + l) * KNN + p0];
            u64 c1 = mg[(1 * 64 + l) * KNN + p1];
            u64 c2 = mg[(2 * 64 + l) * KNN + p2];
            u64 c3 = mg[(3 * 64 + l) * KNN + p3];
            u64 m01 = c0 < c1 ? c0 : c1; int s01 = c0 < c1 ? 0 : 1;
            u64 m23 = c2 < c3 ? c2 : c3; int s23 = c2 < c3 ? 2 : 3;
            u64 mm = m01 < m23 ? m01 : m23;
            int sel = m01 < m23 ? s01 : s23;
            win[l * KNN + j] = (u16)(mm & 0xFFFFu);
            p0 += (sel == 0); p1 += (sel == 1); p2 += (sel == 2); p3 += (sel == 3);
        }
    }
    __syncthreads();

    // gather-sum: wave w handles 16 queries; lane covers channels 2l, 2l+1
    const u16* Xb = X + (size_t)b * N * C2;
    for (int qq = 0; qq < 16; ++qq) {
        int q = w * 16 + qq;
        float f0 = 0.f, f1 = 0.f;
        for (int j = 1; j < KNN; ++j) {               // skip nearest (j=0)
            int m = win[q * KNN + j];
            u32 u2 = *(const u32*)(Xb + (size_t)m * C2 + 2 * l);
            f0 += bf2f((u16)(u2 & 0xFFFFu));
            f1 += bf2f((u16)(u2 >> 16));
        }
        u16* dst = X + ((size_t)b * N + n0 + q) * C2 + 128 + 2 * l;
        *(u32*)dst = ((u32)f2bf(f1) << 16) | (u32)f2bf(f0);
    }
}

// ---------------------------------------------------------------------------
// K3: MFMA GEMM. out[b][o][n] = (W[o][:].X[b][n][:] + bc[o]+20bg[o])/21 + pts.
// Wave tile: 16(o) x 64(n), K=256 = 8 x mfma_f32_16x16x32_bf16 x 4 subtiles.
// A-frag:  Wt[o0+l16][kk*32 + lq*8 ..+8]  (contiguous 16B)
// B-frag:  X[n0+t*16+l16][kk*32 + lq*8 ..+8] (contiguous 16B)
// C/D map: col=lane&15 (n), row=(lane>>4)*4+reg (o)  [m89-verified]
// ---------------------------------------------------------------------------
__global__ __launch_bounds__(256) void k_gemm_mfma(
        const u16* __restrict__ X, const u16* __restrict__ Wt,
        const float* __restrict__ pts, const float* __restrict__ bc,
        const float* __restrict__ bg, float* __restrict__ out) {
    int wid = blockIdx.x * 4 + (threadIdx.x >> 6);   // 0..4095
    int lane = threadIdx.x & 63;
    int ot = wid & 7;            // 8 o-tiles of 16
    int nt = wid >> 3;           // 512 n-tiles of 64
    int b  = nt >> 6;            // 64 n-tiles per batch
    int n0 = (nt & 63) * 64;

    int l16 = lane & 15, lq = lane >> 4;
    const u16* Xb = X + (size_t)b * N * C2;
    const u16* aptr = Wt + (size_t)(ot * 16 + l16) * C2 + lq * 8;
    const u16* bptr0 = Xb + (size_t)(n0 + 0 * 16 + l16) * C2 + lq * 8;
    const u16* bptr1 = Xb + (size_t)(n0 + 1 * 16 + l16) * C2 + lq * 8;
    const u16* bptr2 = Xb + (size_t)(n0 + 2 * 16 + l16) * C2 + lq * 8;
    const u16* bptr3 = Xb + (size_t)(n0 + 3 * 16 + l16) * C2 + lq * 8;

    f32x4 acc0 = {0.f, 0.f, 0.f, 0.f};
    f32x4 acc1 = {0.f, 0.f, 0.f, 0.f};
    f32x4 acc2 = {0.f, 0.f, 0.f, 0.f};
    f32x4 acc3 = {0.f, 0.f, 0.f, 0.f};
    #pragma unroll
    for (int kk = 0; kk < 8; ++kk) {
        bf16x8 a  = *(const bf16x8*)(aptr  + kk * 32);
        bf16x8 b0 = *(const bf16x8*)(bptr0 + kk * 32);
        bf16x8 b1 = *(const bf16x8*)(bptr1 + kk * 32);
        bf16x8 b2 = *(const bf16x8*)(bptr2 + kk * 32);
        bf16x8 b3 = *(const bf16x8*)(bptr3 + kk * 32);
        acc0 = __builtin_amdgcn_mfma_f32_16x16x32_bf16(a, b0, acc0, 0, 0, 0);
        acc1 = __builtin_amdgcn_mfma_f32_16x16x32_bf16(a, b1, acc1, 0, 0, 0);
        acc2 = __builtin_amdgcn_mfma_f32_16x16x32_bf16(a, b2, acc2, 0, 0, 0);
        acc3 = __builtin_amdgcn_mfma_f32_16x16x32_bf16(a, b3, acc3, 0, 0, 0);
    }

    const float inv21 = 1.0f / 21.0f;
    float bias[4];
    #pragma unroll
    for (int r = 0; r < 4; ++r) {
        int o = ot * 16 + lq * 4 + r;
        bias[r] = bc[o] + 20.f * bg[o];
    }
    const float* pb = pts + (size_t)b * C * N;
    float* ob = out + (size_t)b * C * N;
    f32x4 accs[4] = {acc0, acc1, acc2, acc3};
    #pragma unroll
    for (int t = 0; t < 4; ++t) {
        int n = n0 + t * 16 + l16;
        #pragma unroll
        for (int r = 0; r < 4; ++r) {
            int o = ot * 16 + lq * 4 + r;
            ob[(size_t)o * N + n] =
                (accs[t][r] + bias[r]) * inv21 + pb[(size_t)o * N + n];
        }
    }
}

// ---------------------------------------------------------------------------
extern "C" void kernel_launch(void* const* d_in, const int* in_sizes, int n_in,
                              void* d_out, int out_size, void* d_ws, size_t ws_size,
                              hipStream_t stream) {
    const float* xyz = (const float*)d_in[0];
    const float* pts = (const float*)d_in[1];
    const float* Wc  = (const float*)d_in[2];
    const float* bc  = (const float*)d_in[3];
    const float* Wg  = (const float*)d_in[4];
    const float* bg  = (const float*)d_in[5];
    float* out = (float*)d_out;

    char* ws = (char*)d_ws;
    u16* X  = (u16*)ws;                               // B*N*C2 bf16 = 16 MB
    u16* Wt = (u16*)(ws + (size_t)B * N * C2 * 2);    // 256*128 bf16 = 64 KB

    k_transpose_lrelu<<<dim3(N / 32, C / 32, B), dim3(32, 8), 0, stream>>>(pts, X);
    k_pack_w<<<dim3(128), dim3(256), 0, stream>>>(Wc, Wg, Wt);
    k_knn_gather<<<dim3(N / 64, B), dim3(256), 0, stream>>>(xyz, X);
    k_gemm_mfma<<<dim3(1024), dim3(256), 0, stream>>>(X, Wt, pts, bc, bg, out);
}

// Round 5
// 285.738 us; speedup vs baseline: 1.3368x; 1.0710x over previous
//
#include <hip/hip_runtime.h>

// Problem constants
#define B 8
#define N 4096
#define C 128
#define C2 256          // K-dim of fused GEMM: [ptl | s]
#define KNN 21          // top-(K+1), drop nearest
#define CAP 22          // per-lane append buffer capacity (slots 0..21)

typedef unsigned long long u64;
typedef unsigned int u32;
typedef unsigned short u16;

typedef __attribute__((ext_vector_type(8))) short bf16x8;
typedef __attribute__((ext_vector_type(4))) float f32x4;

__device__ __forceinline__ float bf2f(u16 u) {
    return __uint_as_float(((u32)u) << 16);
}
__device__ __forceinline__ u16 f2bf(float f) {  // round-to-nearest-even
    u32 x = __float_as_uint(f);
    return (u16)((x + 0x7FFFu + ((x >> 16) & 1u)) >> 16);
}

// ---------------------------------------------------------------------------
// K1: transpose + leaky_relu: points (B,C,N) f32 -> X[b][n][c] (c<128) bf16
// ---------------------------------------------------------------------------
__global__ __launch_bounds__(256) void k_transpose_lrelu(
        const float* __restrict__ pts, u16* __restrict__ X) {
    __shared__ u16 tile[32][33];
    int b  = blockIdx.z;
    int c0 = blockIdx.y * 32;
    int n0 = blockIdx.x * 32;
    int tx = threadIdx.x, ty = threadIdx.y;   // 32 x 8
    const float* src = pts + (size_t)b * C * N;
    #pragma unroll
    for (int i = 0; i < 32; i += 8) {
        float v = src[(size_t)(c0 + ty + i) * N + n0 + tx];
        if (v < 0.f) v = __fmul_rn(v, 0.01f);
        tile[ty + i][tx] = f2bf(v);
    }
    __syncthreads();
    u16* dst = X + (size_t)b * N * C2;
    #pragma unroll
    for (int i = 0; i < 32; i += 8) {
        dst[(size_t)(n0 + ty + i) * C2 + (c0 + tx)] = tile[tx][ty + i];
    }
}

// ---------------------------------------------------------------------------
// K2: exact KNN (top-21 by (sq, idx), drop min) + neighbor-feature gather-sum.
// 256 thr = 4 waves; 64 queries/block (query = lane); wave w scans candidates
// [w*1024, +1024). Selection: u32 sortable key + parallel idx registers —
// compare-exchange = 1 v_cmp + 4 v_cndmask. Stability (strict compares) keeps
// the smaller index on key ties == np top_k tie-break. Cross-wave merge packs
// (key<<32|idx) u64 so ties resolve by index.
// ---------------------------------------------------------------------------
__global__ __launch_bounds__(256) void k_knn_gather(
        const float* __restrict__ xyz, u16* __restrict__ X) {
    __shared__ __align__(16) char lds[50176];
    float4* stg  = (float4*)lds;                      // [4][256]   16384 B
    u32*    kbuf = (u32*)(lds + 16384);               // [CAP][256] 22528 B
    u16*    ibuf = (u16*)(lds + 16384 + 22528);       // [CAP][256] 11264 B
    u64*    mg   = (u64*)lds;                         // [256][21]  43008 B (phase B)
    __shared__ u16 win[64 * KNN];

    int tid = threadIdx.x;
    int w = tid >> 6, l = tid & 63;
    int b = blockIdx.y;
    int n0 = blockIdx.x * 64;
    int nq = n0 + l;

    const float* xz = xyz + (size_t)b * 3 * N;
    // query point (np formula: ((x*x + y*y) + z*z))
    float qx = xz[nq], qy = xz[N + nq], qz = xz[2 * N + nq];
    float snq = __fadd_rn(__fadd_rn(__fmul_rn(qx, qx), __fmul_rn(qy, qy)),
                          __fmul_rn(qz, qz));

    u32 key[KNN], idx[KNN];
    #pragma unroll
    for (int i = 0; i < KNN; ++i) { key[i] = 0xFFFFFFFFu; idx[i] = 0u; }
    int cnt = 0;
    u32 thr = 0xFFFFFFFFu;
    float4* mystg = stg + w * 256;

    auto compact = [&]() {
        #pragma unroll 1
        for (int i = 0; i < CAP; ++i) {
            if (__ballot(i < cnt) == 0ull) break;
            u32 kv = kbuf[i * 256 + tid];
            u32 iv = ibuf[i * 256 + tid];
            bool ins = (i < cnt) && (kv < key[20]);   // strict: ties keep old
            if (__ballot(ins) != 0ull) {
                key[20] = ins ? kv : key[20];
                idx[20] = ins ? iv : idx[20];
                #pragma unroll
                for (int t = 19; t >= 0; --t) {       // stable bubble (strict >)
                    bool sw = key[t] > key[t + 1];
                    u32 ka = sw ? key[t + 1] : key[t];
                    u32 kz = sw ? key[t] : key[t + 1];
                    u32 ia = sw ? idx[t + 1] : idx[t];
                    u32 iz = sw ? idx[t] : idx[t + 1];
                    key[t] = ka; key[t + 1] = kz;
                    idx[t] = ia; idx[t + 1] = iz;
                }
            }
        }
        cnt = 0;
        thr = key[20];
    };

    for (int sc = 0; sc < 4; ++sc) {
        int m0 = w * 1024 + sc * 256;
        // stage 256 candidates (x,y,z,sq_norm) into this wave's region
        #pragma unroll
        for (int r = 0; r < 4; ++r) {
            int j = l + 64 * r, m = m0 + j;
            float x = xz[m], y = xz[N + m], z = xz[2 * N + m];
            float sn = __fadd_rn(__fadd_rn(__fmul_rn(x, x), __fmul_rn(y, y)),
                                 __fmul_rn(z, z));
            mystg[j] = make_float4(x, y, z, sn);
        }
        asm volatile("s_waitcnt lgkmcnt(0)" ::: "memory");
        for (int cc = 0; cc < 256; cc += 8) {
            #pragma unroll
            for (int j = 0; j < 8; ++j) {
                float4 cp = mystg[cc + j];            // wave-broadcast read
                int m = m0 + cc + j;
                float dot = __fadd_rn(__fadd_rn(__fmul_rn(qx, cp.x),
                                                __fmul_rn(qy, cp.y)),
                                      __fmul_rn(qz, cp.z));
                float sq = __fadd_rn(__fsub_rn(snq, __fadd_rn(dot, dot)), cp.w);
                u32 bits = __float_as_uint(sq);
                u32 kb = bits ^ (0x80000000u | (u32)(((int)bits) >> 31));
                kbuf[cnt * 256 + tid] = kb;           // unconditional append
                ibuf[cnt * 256 + tid] = (u16)m;
                cnt += (kb < thr);                    // strict: ties dropped
            }
            if (__ballot(cnt >= 15) != 0ull) compact();
        }
    }
    compact();

    __syncthreads();                                  // phase-A buffers dead
    #pragma unroll
    for (int j = 0; j < KNN; ++j)
        mg[(w * 64 + l) * KNN + j] = ((u64)key[j] << 32) | (u64)idx[j];
    __syncthreads();

    if (w == 0) {                                     // 4-way merge per query
        int p0 = 0, p1 = 0, p2 = 0, p3 = 0;
        for (int j = 0; j < KNN; ++j) {
            u64 c0 = mg[(0 * 64 + l) * KNN + p0];
            u64 c1 = mg[(1 * 64 + l) * KNN + p1];
            u64 c2 = mg[(2 * 64 + l) * KNN + p2];
            u64 c3 = mg[(3 * 64 + l) * KNN + p3];
            u64 m01 = c0 < c1 ? c0 : c1; int s01 = c0 < c1 ? 0 : 1;
            u64 m23 = c2 < c3 ? c2 : c3; int s23 = c2 < c3 ? 2 : 3;
            u64 mm = m01 < m23 ? m01 : m23;
            int sel = m01 < m23 ? s01 : s23;
            win[l * KNN + j] = (u16)(mm & 0xFFFFu);
            p0 += (sel == 0); p1 += (sel == 1); p2 += (sel == 2); p3 += (sel == 3);
        }
    }
    __syncthreads();

    // gather-sum: wave w handles 16 queries; lane covers channels 2l, 2l+1
    const u16* Xb = X + (size_t)b * N * C2;
    for (int qq = 0; qq < 16; ++qq) {
        int q = w * 16 + qq;
        float f0 = 0.f, f1 = 0.f;
        #pragma unroll
        for (int j = 1; j < KNN; ++j) {               // skip nearest (j=0)
            int m = win[q * KNN + j];
            u32 u2 = *(const u32*)(Xb + (size_t)m * C2 + 2 * l);
            f0 += bf2f((u16)(u2 & 0xFFFFu));
            f1 += bf2f((u16)(u2 >> 16));
        }
        u16* dst = X + ((size_t)b * N + n0 + q) * C2 + 128 + 2 * l;
        *(u32*)dst = ((u32)f2bf(f1) << 16) | (u32)f2bf(f0);
    }
}

// ---------------------------------------------------------------------------
// K3: MFMA GEMM. out[b][o][n] = (W[o][:].X[b][n][:] + bc[o]+20bg[o])/21 + pts.
// Wave tile: 16(o) x 64(n), K=256 = 8 x mfma_f32_16x16x32_bf16 x 4 subtiles.
// A-frag loaded DIRECTLY from Wc (kk<4) / Wg (kk>=4) fp32 rows, cvt to bf16
// with the same f2bf as the old pack kernel (bit-identical).
// C/D map: col=lane&15 (n), row=(lane>>4)*4+reg (o)  [m89-verified]
// ---------------------------------------------------------------------------
__global__ __launch_bounds__(256) void k_gemm_mfma(
        const u16* __restrict__ X, const float* __restrict__ Wc,
        const float* __restrict__ Wg, const float* __restrict__ pts,
        const float* __restrict__ bc, const float* __restrict__ bg,
        float* __restrict__ out) {
    int wid = blockIdx.x * 4 + (threadIdx.x >> 6);   // 0..4095
    int lane = threadIdx.x & 63;
    int ot = wid & 7;            // 8 o-tiles of 16
    int nt = wid >> 3;           // 512 n-tiles of 64
    int b  = nt >> 6;            // 64 n-tiles per batch
    int n0 = (nt & 63) * 64;

    int l16 = lane & 15, lq = lane >> 4;
    const u16* Xb = X + (size_t)b * N * C2;
    const u16* bptr0 = Xb + (size_t)(n0 + 0 * 16 + l16) * C2 + lq * 8;
    const u16* bptr1 = Xb + (size_t)(n0 + 1 * 16 + l16) * C2 + lq * 8;
    const u16* bptr2 = Xb + (size_t)(n0 + 2 * 16 + l16) * C2 + lq * 8;
    const u16* bptr3 = Xb + (size_t)(n0 + 3 * 16 + l16) * C2 + lq * 8;
    const float* wrowc = Wc + (size_t)(ot * 16 + l16) * 128 + lq * 8;
    const float* wrowg = Wg + (size_t)(ot * 16 + l16) * 128 + lq * 8;

    f32x4 acc0 = {0.f, 0.f, 0.f, 0.f};
    f32x4 acc1 = {0.f, 0.f, 0.f, 0.f};
    f32x4 acc2 = {0.f, 0.f, 0.f, 0.f};
    f32x4 acc3 = {0.f, 0.f, 0.f, 0.f};
    #pragma unroll
    for (int kk = 0; kk < 8; ++kk) {
        const float* ws = (kk < 4) ? (wrowc + kk * 32) : (wrowg + (kk - 4) * 32);
        float4 wa = *(const float4*)ws;
        float4 wb = *(const float4*)(ws + 4);
        bf16x8 a;
        a[0] = (short)f2bf(wa.x); a[1] = (short)f2bf(wa.y);
        a[2] = (short)f2bf(wa.z); a[3] = (short)f2bf(wa.w);
        a[4] = (short)f2bf(wb.x); a[5] = (short)f2bf(wb.y);
        a[6] = (short)f2bf(wb.z); a[7] = (short)f2bf(wb.w);
        bf16x8 b0 = *(const bf16x8*)(bptr0 + kk * 32);
        bf16x8 b1 = *(const bf16x8*)(bptr1 + kk * 32);
        bf16x8 b2 = *(const bf16x8*)(bptr2 + kk * 32);
        bf16x8 b3 = *(const bf16x8*)(bptr3 + kk * 32);
        acc0 = __builtin_amdgcn_mfma_f32_16x16x32_bf16(a, b0, acc0, 0, 0, 0);
        acc1 = __builtin_amdgcn_mfma_f32_16x16x32_bf16(a, b1, acc1, 0, 0, 0);
        acc2 = __builtin_amdgcn_mfma_f32_16x16x32_bf16(a, b2, acc2, 0, 0, 0);
        acc3 = __builtin_amdgcn_mfma_f32_16x16x32_bf16(a, b3, acc3, 0, 0, 0);
    }

    const float inv21 = 1.0f / 21.0f;
    float bias[4];
    #pragma unroll
    for (int r = 0; r < 4; ++r) {
        int o = ot * 16 + lq * 4 + r;
        bias[r] = bc[o] + 20.f * bg[o];
    }
    const float* pb = pts + (size_t)b * C * N;
    float* ob = out + (size_t)b * C * N;
    f32x4 accs[4] = {acc0, acc1, acc2, acc3};
    #pragma unroll
    for (int t = 0; t < 4; ++t) {
        int n = n0 + t * 16 + l16;
        #pragma unroll
        for (int r = 0; r < 4; ++r) {
            int o = ot * 16 + lq * 4 + r;
            ob[(size_t)o * N + n] =
                (accs[t][r] + bias[r]) * inv21 + pb[(size_t)o * N + n];
        }
    }
}

// ---------------------------------------------------------------------------
extern "C" void kernel_launch(void* const* d_in, const int* in_sizes, int n_in,
                              void* d_out, int out_size, void* d_ws, size_t ws_size,
                              hipStream_t stream) {
    const float* xyz = (const float*)d_in[0];
    const float* pts = (const float*)d_in[1];
    const float* Wc  = (const float*)d_in[2];
    const float* bc  = (const float*)d_in[3];
    const float* Wg  = (const float*)d_in[4];
    const float* bg  = (const float*)d_in[5];
    float* out = (float*)d_out;

    u16* X = (u16*)d_ws;                              // B*N*C2 bf16 = 16 MB

    k_transpose_lrelu<<<dim3(N / 32, C / 32, B), dim3(32, 8), 0, stream>>>(pts, X);
    k_knn_gather<<<dim3(N / 64, B), dim3(256), 0, stream>>>(xyz, X);
    k_gemm_mfma<<<dim3(1024), dim3(256), 0, stream>>>(X, Wc, Wg, pts, bc, bg, out);
}